// Round 3
// baseline (47.672 us; speedup 1.0000x reference)
//
#include <hip/hip_runtime.h>
#include <hip/hip_bf16.h>

// Fused: embedding-mean + cont matvec/ReLU + masked prefix-mean pooling + MLP(128->64->2)
// One block per sample b, 256 threads = 4 waves.
//
// Key idea: the cat-embedding mean is LINEAR in the (tiny) tables:
//   pooled_cat[d] = (1/(7*len)) * sum_r count_r * e_r[d],  101 total rows.
// So the main loop builds a 101-bin histogram via wave64 ballot+popcount
// (no gathers, no LDS), and a single 101-row weighted matvec at the end
// reconstructs pooled_cat. Only the cont ReLU path needs per-row work.

#define CARD0 2
#define CARD1 2
#define CARD2 2
#define CARD3 11
#define CARD4 19
#define CARD5 31
#define CARD6 34

__global__ __launch_bounds__(256) void mlp_regressor_fused(
    const float* __restrict__ cont_x,   // [B,S,5]
    const int*   __restrict__ cat_x,    // [B,S,7]
    const int*   __restrict__ length,   // [B]
    const float* __restrict__ e0, const float* __restrict__ e1,
    const float* __restrict__ e2, const float* __restrict__ e3,
    const float* __restrict__ e4, const float* __restrict__ e5,
    const float* __restrict__ e6,
    const float* __restrict__ W_cont,   // [5,64]
    const float* __restrict__ b_cont,   // [64]
    const float* __restrict__ W1,       // [128,64]
    const float* __restrict__ b1,       // [64]
    const float* __restrict__ W2,       // [64,2]
    const float* __restrict__ b2,       // [2]
    float*       __restrict__ out,      // [B,2]
    int S)
{
    constexpr int CARD[7] = {CARD0, CARD1, CARD2, CARD3, CARD4, CARD5, CARD6};
    constexpr int OFFB[7] = {0, 2, 4, 6, 17, 36, 67};   // flat bin offsets, total 101

    __shared__ int    cnt[4][104];
    __shared__ float  wlds[104];
    __shared__ float  pcat[4][64];
    __shared__ __align__(16) float4 pcont4[4][16];
    __shared__ float  pooled[128];
    __shared__ float  partW1[4][64];
    __shared__ float  hvec[64];

    const int b   = blockIdx.x;
    const int tid = threadIdx.x;
    const int g   = tid >> 6;    // wave id 0..3
    const int l   = tid & 63;    // lane
    const int rg  = l >> 4;      // row-in-quad 0..3
    const int q   = l & 15;      // dim-quad: dims 4q..4q+3

    const int len = length[b];

    // per-lane W_cont columns for dims 4q..4q+3
    const float4* Wc4 = (const float4*)W_cont;   // [5][16] float4
    float4 wc0  = Wc4[0 * 16 + q];
    float4 wc1  = Wc4[1 * 16 + q];
    float4 wc2  = Wc4[2 * 16 + q];
    float4 wc3  = Wc4[3 * 16 + q];
    float4 wc4v = Wc4[4 * 16 + q];
    float4 bc4  = ((const float4*)b_cont)[q];

    const int*   catp  = cat_x  + (size_t)b * S * 7;
    const float* contp = cont_x + (size_t)b * S * 5;

    int    cacc0 = 0, cacc1 = 0;                 // lane-sliced histogram
    float4 acc_cont = {0.f, 0.f, 0.f, 0.f};

    for (int base = g * 64; base < len; base += 256) {
        const int rows = min(64, len - base);

        // coalesced-ish stage: lane = row
        int   id[7];
        float xv[5];
        if (l < rows) {
            const int* cp = catp + (size_t)(base + l) * 7;
#pragma unroll
            for (int t = 0; t < 7; ++t) id[t] = cp[t];
            const float* xp = contp + (size_t)(base + l) * 5;
#pragma unroll
            for (int j = 0; j < 5; ++j) xv[j] = xp[j];
        } else {
#pragma unroll
            for (int t = 0; t < 7; ++t) id[t] = 0;
#pragma unroll
            for (int j = 0; j < 5; ++j) xv[j] = 0.f;
        }

        const unsigned long long vmask = __ballot(l < rows);

        // ---- histogram via ballot+popc: 101 bins, no DS ops ----
#pragma unroll
        for (int t = 0; t < 7; ++t) {
#pragma unroll
            for (int v = 0; v < CARD[t]; ++v) {
                const int i = OFFB[t] + v;   // compile-time
                const int c = __popcll(__ballot(id[t] == v) & vmask);
                if (i < 64) { if (l == i)      cacc0 += c; }
                else        { if (l == i - 64) cacc1 += c; }
            }
        }

        // ---- cont ReLU path: quads of 4 rows x 16 dim-quads ----
        const int quads = (rows + 3) >> 2;
        for (int r4 = 0; r4 < quads; ++r4) {
            const int rr = r4 * 4 + rg;

            float bx0 = __shfl(xv[0], rr);
            float bx1 = __shfl(xv[1], rr);
            float bx2 = __shfl(xv[2], rr);
            float bx3 = __shfl(xv[3], rr);
            float bx4 = __shfl(xv[4], rr);

            float4 ch = bc4;
            ch.x = fmaf(bx0, wc0.x, ch.x); ch.y = fmaf(bx0, wc0.y, ch.y);
            ch.z = fmaf(bx0, wc0.z, ch.z); ch.w = fmaf(bx0, wc0.w, ch.w);
            ch.x = fmaf(bx1, wc1.x, ch.x); ch.y = fmaf(bx1, wc1.y, ch.y);
            ch.z = fmaf(bx1, wc1.z, ch.z); ch.w = fmaf(bx1, wc1.w, ch.w);
            ch.x = fmaf(bx2, wc2.x, ch.x); ch.y = fmaf(bx2, wc2.y, ch.y);
            ch.z = fmaf(bx2, wc2.z, ch.z); ch.w = fmaf(bx2, wc2.w, ch.w);
            ch.x = fmaf(bx3, wc3.x, ch.x); ch.y = fmaf(bx3, wc3.y, ch.y);
            ch.z = fmaf(bx3, wc3.z, ch.z); ch.w = fmaf(bx3, wc3.w, ch.w);
            ch.x = fmaf(bx4, wc4v.x, ch.x); ch.y = fmaf(bx4, wc4v.y, ch.y);
            ch.z = fmaf(bx4, wc4v.z, ch.z); ch.w = fmaf(bx4, wc4v.w, ch.w);

            if (rr < rows) {
                acc_cont.x += fmaxf(ch.x, 0.f);
                acc_cont.y += fmaxf(ch.y, 0.f);
                acc_cont.z += fmaxf(ch.z, 0.f);
                acc_cont.w += fmaxf(ch.w, 0.f);
            }
        }
    }

    // ---- cont reduce over rg (lanes ^16, ^32) ----
#pragma unroll
    for (int off = 16; off <= 32; off <<= 1) {
        acc_cont.x += __shfl_xor(acc_cont.x, off);
        acc_cont.y += __shfl_xor(acc_cont.y, off);
        acc_cont.z += __shfl_xor(acc_cont.z, off);
        acc_cont.w += __shfl_xor(acc_cont.w, off);
    }
    if (rg == 0) pcont4[g][q] = acc_cont;   // dims 4q..4q+3

    cnt[g][l] = cacc0;
    if (l < 40) cnt[g][64 + l] = cacc1;
    __syncthreads();

    if (tid < 101) {
        const float inv7len = 1.0f / (7.0f * (float)len);
        wlds[tid] = (float)(cnt[0][tid] + cnt[1][tid] + cnt[2][tid] + cnt[3][tid]) * inv7len;
    }
    __syncthreads();

    // ---- weighted 101-row embedding matvec, bins striped over waves ----
    {
        const float* tabs[7] = {e0, e1, e2, e3, e4, e5, e6};
        float pc = 0.f;
#pragma unroll
        for (int t = 0; t < 7; ++t) {
#pragma unroll
            for (int v = 0; v < CARD[t]; ++v) {
                const int i = OFFB[t] + v;          // compile-time
                if ((i & 3) == g) {                  // wave-uniform branch
                    pc = fmaf(wlds[i], tabs[t][v * 64 + l], pc);
                }
            }
        }
        pcat[g][l] = pc;
    }
    __syncthreads();

    if (tid < 128) {
        if (tid < 64) {
            pooled[tid] = pcat[0][tid] + pcat[1][tid] + pcat[2][tid] + pcat[3][tid];
        } else {
            const float* pf = (const float*)pcont4;  // [4][64]
            const int d = tid - 64;
            pooled[tid] = (pf[d] + pf[64 + d] + pf[128 + d] + pf[192 + d])
                          * (1.0f / (float)len);
        }
    }
    __syncthreads();

    // ---- h = relu(pooled @ W1 + b1), 128 dims split over 4 wave-segments ----
    {
        const int o   = tid & 63;
        const int seg = tid >> 6;
        float a1 = (seg == 0) ? b1[o] : 0.f;
        const int d0 = seg * 32;
#pragma unroll 8
        for (int i = 0; i < 32; ++i) {
            const int d = d0 + i;
            a1 = fmaf(pooled[d], W1[d * 64 + o], a1);
        }
        partW1[seg][o] = a1;
    }
    __syncthreads();
    if (tid < 64) {
        hvec[tid] = fmaxf(partW1[0][tid] + partW1[1][tid]
                        + partW1[2][tid] + partW1[3][tid], 0.f);
    }
    __syncthreads();

    if (tid < 2) {
        float acc = b2[tid];
#pragma unroll
        for (int j = 0; j < 64; ++j) {
            acc = fmaf(hvec[j], W2[j * 2 + tid], acc);
        }
        out[b * 2 + tid] = fmaxf(acc, 0.f);
    }
}

extern "C" void kernel_launch(void* const* d_in, const int* in_sizes, int n_in,
                              void* d_out, int out_size, void* d_ws, size_t ws_size,
                              hipStream_t stream)
{
    const float* cont_x = (const float*)d_in[0];
    const int*   cat_x  = (const int*)d_in[1];
    const int*   length = (const int*)d_in[2];
    const float* e0     = (const float*)d_in[3];
    const float* e1     = (const float*)d_in[4];
    const float* e2     = (const float*)d_in[5];
    const float* e3     = (const float*)d_in[6];
    const float* e4     = (const float*)d_in[7];
    const float* e5     = (const float*)d_in[8];
    const float* e6     = (const float*)d_in[9];
    const float* W_cont = (const float*)d_in[10];
    const float* b_cont = (const float*)d_in[11];
    const float* W1     = (const float*)d_in[12];
    const float* b1     = (const float*)d_in[13];
    const float* W2     = (const float*)d_in[14];
    const float* b2     = (const float*)d_in[15];
    float*       out    = (float*)d_out;

    const int B = in_sizes[2];                 // 2048
    const int S = in_sizes[0] / (B * 5);       // 512

    hipLaunchKernelGGL(mlp_regressor_fused, dim3(B), dim3(256), 0, stream,
                       cont_x, cat_x, length,
                       e0, e1, e2, e3, e4, e5, e6,
                       W_cont, b_cont, W1, b1, W2, b2,
                       out, S);
}

// Round 4
// 31.061 us; speedup vs baseline: 1.5348x; 1.5348x over previous
//
#include <hip/hip_runtime.h>
#include <hip/hip_bf16.h>

// Two-kernel fused MLPRegressor:
//  K1 (block=sample, 256 thr): histogram-based cat-embedding mean + cont ReLU
//     prefix-sum -> pooled[B][128] in d_ws.
//     - binary cols (card 2): packed per-lane register sums (count0 = len - count1)
//     - big cols: per-wave LDS ds_add histogram (95 bins)
//     - cont path: quads of 4 rows x 16 dim-quads, 5 bpermute broadcasts/quad
//  K2 (wave=sample, 64 thr): pooled @ W1 + b1 -> relu -> @ W2 + b2 -> relu.
//     pooled row is wave-uniform -> s_load; W1 coalesced; butterfly for W2.

#define CARD0 2
#define CARD1 2
#define CARD2 2
#define CARD3 11
#define CARD4 19
#define CARD5 31
#define CARD6 34

__global__ __launch_bounds__(256) void mlp_pool_kernel(
    const float* __restrict__ cont_x,   // [B,S,5]
    const int*   __restrict__ cat_x,    // [B,S,7]
    const int*   __restrict__ length,   // [B]
    const float* __restrict__ e0, const float* __restrict__ e1,
    const float* __restrict__ e2, const float* __restrict__ e3,
    const float* __restrict__ e4, const float* __restrict__ e5,
    const float* __restrict__ e6,
    const float* __restrict__ W_cont,   // [5,64]
    const float* __restrict__ b_cont,   // [64]
    float*       __restrict__ pooled_g, // [B,128] workspace
    int S)
{
    constexpr int CARD[7] = {CARD0, CARD1, CARD2, CARD3, CARD4, CARD5, CARD6};
    constexpr int OFFB[7] = {0, 2, 4, 6, 17, 36, 67};   // flat bin offsets (101 total)
    constexpr int HOFF[4] = {0, 11, 30, 61};            // big-table hist offsets (95)

    __shared__ int    hist[4][96];     // per-wave big-table histograms
    __shared__ int    bcnt[4];         // per-wave packed binary counts
    __shared__ float  wlds[104];       // 101 bin weights
    __shared__ float  pcat[4][64];
    __shared__ __align__(16) float4 pcont4[4][16];

    const int b   = blockIdx.x;
    const int tid = threadIdx.x;
    const int g   = tid >> 6;    // wave id 0..3
    const int l   = tid & 63;    // lane
    const int rg  = l >> 4;      // row-in-quad 0..3
    const int q   = l & 15;      // dim-quad: dims 4q..4q+3

    // zero per-wave histograms
    {
        int* hz = &hist[0][0];
        for (int i = tid; i < 4 * 96; i += 256) hz[i] = 0;
    }

    const int len = length[b];

    const float4* Wc4 = (const float4*)W_cont;   // [5][16] float4
    float4 wc0  = Wc4[0 * 16 + q];
    float4 wc1  = Wc4[1 * 16 + q];
    float4 wc2  = Wc4[2 * 16 + q];
    float4 wc3  = Wc4[3 * 16 + q];
    float4 wc4v = Wc4[4 * 16 + q];
    float4 bc4  = ((const float4*)b_cont)[q];

    const int*   catp  = cat_x  + (size_t)b * S * 7;
    const float* contp = cont_x + (size_t)b * S * 5;

    int    pk_acc = 0;                           // packed binary counts (3x 8-bit)
    float4 acc_cont = {0.f, 0.f, 0.f, 0.f};

    __syncthreads();   // hist zeroed

    for (int base = g * 64; base < len; base += 256) {
        const int rows = min(64, len - base);

        int   id[7];
        float xv[5];
        if (l < rows) {
            const int* cp = catp + (base + l) * 7;
#pragma unroll
            for (int t = 0; t < 7; ++t) id[t] = cp[t];
            const float* xp = contp + (base + l) * 5;
#pragma unroll
            for (int j = 0; j < 5; ++j) xv[j] = xp[j];
        } else {
#pragma unroll
            for (int t = 0; t < 7; ++t) id[t] = 0;
#pragma unroll
            for (int j = 0; j < 5; ++j) xv[j] = 0.f;
        }

        // binary columns: packed register sum (invalid lanes contribute 0)
        pk_acc += id[0] + (id[1] << 8) + (id[2] << 16);

        // big columns: per-wave LDS atomic histogram
        if (l < rows) {
            atomicAdd(&hist[g][HOFF[0] + id[3]], 1);
            atomicAdd(&hist[g][HOFF[1] + id[4]], 1);
            atomicAdd(&hist[g][HOFF[2] + id[5]], 1);
            atomicAdd(&hist[g][HOFF[3] + id[6]], 1);
        }

        // cont ReLU path: quads of 4 rows x 16 dim-quads
        const int quads = (rows + 3) >> 2;
        for (int r4 = 0; r4 < quads; ++r4) {
            const int rr = r4 * 4 + rg;

            float bx0 = __shfl(xv[0], rr);
            float bx1 = __shfl(xv[1], rr);
            float bx2 = __shfl(xv[2], rr);
            float bx3 = __shfl(xv[3], rr);
            float bx4 = __shfl(xv[4], rr);

            float4 ch = bc4;
            ch.x = fmaf(bx0, wc0.x, ch.x); ch.y = fmaf(bx0, wc0.y, ch.y);
            ch.z = fmaf(bx0, wc0.z, ch.z); ch.w = fmaf(bx0, wc0.w, ch.w);
            ch.x = fmaf(bx1, wc1.x, ch.x); ch.y = fmaf(bx1, wc1.y, ch.y);
            ch.z = fmaf(bx1, wc1.z, ch.z); ch.w = fmaf(bx1, wc1.w, ch.w);
            ch.x = fmaf(bx2, wc2.x, ch.x); ch.y = fmaf(bx2, wc2.y, ch.y);
            ch.z = fmaf(bx2, wc2.z, ch.z); ch.w = fmaf(bx2, wc2.w, ch.w);
            ch.x = fmaf(bx3, wc3.x, ch.x); ch.y = fmaf(bx3, wc3.y, ch.y);
            ch.z = fmaf(bx3, wc3.z, ch.z); ch.w = fmaf(bx3, wc3.w, ch.w);
            ch.x = fmaf(bx4, wc4v.x, ch.x); ch.y = fmaf(bx4, wc4v.y, ch.y);
            ch.z = fmaf(bx4, wc4v.z, ch.z); ch.w = fmaf(bx4, wc4v.w, ch.w);

            if (rr < rows) {
                acc_cont.x += fmaxf(ch.x, 0.f);
                acc_cont.y += fmaxf(ch.y, 0.f);
                acc_cont.z += fmaxf(ch.z, 0.f);
                acc_cont.w += fmaxf(ch.w, 0.f);
            }
        }
    }

    // reduce packed binary counts across lanes (fields stay < 256)
#pragma unroll
    for (int off = 1; off <= 32; off <<= 1) pk_acc += __shfl_xor(pk_acc, off);
    if (l == 0) bcnt[g] = pk_acc;

    // cont reduce over rg (lanes ^16, ^32)
#pragma unroll
    for (int off = 16; off <= 32; off <<= 1) {
        acc_cont.x += __shfl_xor(acc_cont.x, off);
        acc_cont.y += __shfl_xor(acc_cont.y, off);
        acc_cont.z += __shfl_xor(acc_cont.z, off);
        acc_cont.w += __shfl_xor(acc_cont.w, off);
    }
    if (rg == 0) pcont4[g][q] = acc_cont;

    __syncthreads();

    const float inv7len = 1.0f / (7.0f * (float)len);
    if (tid < 95) {
        const int s = hist[0][tid] + hist[1][tid] + hist[2][tid] + hist[3][tid];
        wlds[6 + tid] = (float)s * inv7len;
    }
    if (tid < 3) {
        const int c1 = ((bcnt[0] >> (8 * tid)) & 0xFF) + ((bcnt[1] >> (8 * tid)) & 0xFF)
                     + ((bcnt[2] >> (8 * tid)) & 0xFF) + ((bcnt[3] >> (8 * tid)) & 0xFF);
        wlds[2 * tid + 1] = (float)c1 * inv7len;
        wlds[2 * tid]     = (float)(len - c1) * inv7len;
    }
    __syncthreads();

    // weighted 101-row embedding matvec, bins striped over waves
    {
        float pc = 0.f;
#pragma unroll
        for (int t = 0; t < 7; ++t) {
            const float* tab = (t == 0) ? e0 : (t == 1) ? e1 : (t == 2) ? e2
                             : (t == 3) ? e3 : (t == 4) ? e4 : (t == 5) ? e5 : e6;
#pragma unroll
            for (int v = 0; v < CARD[t]; ++v) {
                const int i = OFFB[t] + v;          // compile-time
                if ((i & 3) == g) {
                    pc = fmaf(wlds[i], tab[v * 64 + l], pc);
                }
            }
        }
        pcat[g][l] = pc;
    }
    __syncthreads();

    if (tid < 128) {
        float v;
        if (tid < 64) {
            v = pcat[0][tid] + pcat[1][tid] + pcat[2][tid] + pcat[3][tid];
        } else {
            const float* pf = (const float*)pcont4;  // [4][64]
            const int d = tid - 64;
            v = (pf[d] + pf[64 + d] + pf[128 + d] + pf[192 + d]) * (1.0f / (float)len);
        }
        pooled_g[b * 128 + tid] = v;
    }
}

__global__ __launch_bounds__(64) void mlp_head_kernel(
    const float* __restrict__ pooled_g, // [B,128]
    const float* __restrict__ W1,       // [128,64]
    const float* __restrict__ b1,       // [64]
    const float* __restrict__ W2,       // [64,2]
    const float* __restrict__ b2,       // [2]
    float*       __restrict__ out)      // [B,2]
{
    const int s = blockIdx.x;
    const int o = threadIdx.x;          // output unit 0..63

    const float* prow = pooled_g + s * 128;   // wave-uniform -> s_loads

    float acc = b1[o];
#pragma unroll 16
    for (int d = 0; d < 128; ++d) {
        acc = fmaf(prow[d], W1[d * 64 + o], acc);
    }
    const float h = fmaxf(acc, 0.f);

    const float2 w2 = ((const float2*)W2)[o];
    float r0 = h * w2.x;
    float r1 = h * w2.y;
#pragma unroll
    for (int off = 1; off <= 32; off <<= 1) {
        r0 += __shfl_xor(r0, off);
        r1 += __shfl_xor(r1, off);
    }
    if (o == 0) {
        const float2 bb = *(const float2*)b2;
        float2 res;
        res.x = fmaxf(r0 + bb.x, 0.f);
        res.y = fmaxf(r1 + bb.y, 0.f);
        ((float2*)out)[s] = res;
    }
}

extern "C" void kernel_launch(void* const* d_in, const int* in_sizes, int n_in,
                              void* d_out, int out_size, void* d_ws, size_t ws_size,
                              hipStream_t stream)
{
    const float* cont_x = (const float*)d_in[0];
    const int*   cat_x  = (const int*)d_in[1];
    const int*   length = (const int*)d_in[2];
    const float* e0     = (const float*)d_in[3];
    const float* e1     = (const float*)d_in[4];
    const float* e2     = (const float*)d_in[5];
    const float* e3     = (const float*)d_in[6];
    const float* e4     = (const float*)d_in[7];
    const float* e5     = (const float*)d_in[8];
    const float* e6     = (const float*)d_in[9];
    const float* W_cont = (const float*)d_in[10];
    const float* b_cont = (const float*)d_in[11];
    const float* W1     = (const float*)d_in[12];
    const float* b1     = (const float*)d_in[13];
    const float* W2     = (const float*)d_in[14];
    const float* b2     = (const float*)d_in[15];
    float*       out    = (float*)d_out;

    const int B = in_sizes[2];                 // 2048
    const int S = in_sizes[0] / (B * 5);       // 512

    float* pooled_ws = (float*)d_ws;           // needs B*128*4 = 1 MB

    hipLaunchKernelGGL(mlp_pool_kernel, dim3(B), dim3(256), 0, stream,
                       cont_x, cat_x, length,
                       e0, e1, e2, e3, e4, e5, e6,
                       W_cont, b_cont, pooled_ws, S);

    hipLaunchKernelGGL(mlp_head_kernel, dim3(B), dim3(64), 0, stream,
                       pooled_ws, W1, b1, W2, b2, out);
}